// Round 15
// baseline (673.899 us; speedup 1.0000x reference)
//
#include <hip/hip_runtime.h>
#include <hip/hip_bf16.h>

#define BH 32
#define SQ 2048
#define DD 128
#define SCALE 0.08838834764831845f

typedef short bf16x8 __attribute__((ext_vector_type(8)));
typedef unsigned short us8 __attribute__((ext_vector_type(8)));
typedef float f32x4 __attribute__((ext_vector_type(4)));

typedef __attribute__((address_space(1))) const unsigned gu32;
typedef __attribute__((address_space(3))) unsigned lu32;
__device__ __forceinline__ void gll16(const void* g, void* l) {
    __builtin_amdgcn_global_load_lds((gu32*)g, (lu32*)l, 16, 0, 0);
}

__device__ __forceinline__ unsigned short f2bf(float f) {
    unsigned u = __float_as_uint(f);
    u = u + 0x7FFFu + ((u >> 16) & 1u);   // RNE
    return (unsigned short)(u >> 16);
}
__device__ __forceinline__ float bf2f(unsigned short h) {
    return __uint_as_float(((unsigned)h) << 16);
}

// mask elem width detect: int32 {0,1} has zero bytes at off%4!=0
__device__ __forceinline__ int mask_byte_shift(const void* m) {
    const unsigned char* p = (const unsigned char*)m;
    int l = threadIdx.x & 63;
    unsigned char v = p[l];
    unsigned long long nz = __ballot(((l & 3) != 0) && (v != 0));
    return (nz != 0ull) ? 0 : 2;
}

// bias-transpose LDS swizzle: 8-block-preserving XOR, conflict-free both phases
__device__ __forceinline__ int bswz(int row) {
    return ((((row) >> 2) & 7) ^ ((row) & 3)) << 3;
}

// ---------------- merged prep: VT transpose | QK cvt | bias+mask xform ----------------
#define VT_LD 136
#define XB_LD 522
__global__ __launch_bounds__(512) void prep_all(
    const float* __restrict__ q, const float* __restrict__ k, const float* __restrict__ v,
    const float* __restrict__ bias, const void* __restrict__ mask,
    unsigned short* __restrict__ qb, unsigned short* __restrict__ kb,
    unsigned short* __restrict__ vt, unsigned short* __restrict__ biasT) {
    __shared__ char lds[128 * VT_LD * 2];   // union: VT tile (34816B) / bias T (32768B)
    int t = threadIdx.x;   // 512
    int bid = blockIdx.x;
    if (bid < 512) {
        // ---- V transpose tile ----
        unsigned short* tile = (unsigned short*)lds;
        int b = bid >> 4;
        int kt = bid & 15;
        size_t vbase = ((size_t)b * SQ + (size_t)kt * 128) * DD;
        for (int i = 0; i < 8; ++i) {
            size_t fi = (size_t)i * 2048 + (size_t)t * 4;
            float4 val = *(const float4*)(v + vbase + fi);
            int kk = (int)(fi >> 7);
            int d0 = (int)(fi & 127);
            tile[(d0 + 0) * VT_LD + kk] = f2bf(val.x);
            tile[(d0 + 1) * VT_LD + kk] = f2bf(val.y);
            tile[(d0 + 2) * VT_LD + kk] = f2bf(val.z);
            tile[(d0 + 3) * VT_LD + kk] = f2bf(val.w);
        }
        __syncthreads();
        int d = t >> 2, ks = (t & 3) * 32;
        size_t obase = (size_t)b * (DD * SQ) + (size_t)d * SQ + (size_t)kt * 128 + ks;
        const unsigned short* row = tile + d * VT_LD + ks;
        #pragma unroll
        for (int j = 0; j < 4; ++j)
            *(int4*)(vt + obase + j * 8) = *(const int4*)(row + j * 8);
    } else if (bid < 1024) {
        // ---- Q,K convert (grid-stride over 512 blocks) ----
        const size_t n4 = (size_t)BH * SQ * DD / 4;
        size_t i = (size_t)(bid - 512) * 512 + t;
        const size_t stride = 512 * 512;
        for (; i < 2 * n4; i += stride) {
            const float4* src = (i < n4) ? (const float4*)q : (const float4*)k;
            unsigned short* dst = (i < n4) ? qb : kb;
            size_t j = (i < n4) ? i : i - n4;
            float4 val = src[j];
            ushort4 o;
            o.x = f2bf(val.x); o.y = f2bf(val.y); o.z = f2bf(val.z); o.w = f2bf(val.w);
            *(ushort4*)(dst + j * 4) = o;
        }
    } else {
        // ---- biasT[b][q][k] = mask ? -1e18 : bias (bf16) ----
        // flat T[32][512], column swizzled by bswz(row): conflict-free writes
        // (8 distinct banks across the 8 threads sharing a column) and aligned
        // us8 vector reads (8-block-preserving XOR).
        unsigned short* T = (unsigned short*)lds;
        int xb = bid - 1024;                 // 0..8191
        int qq = xb >> 2, kc = xb & 3;
        int k0 = kc * 512;
        int mshift = mask_byte_shift(mask);
        const float4* src = (const float4*)(bias + ((size_t)qq * SQ + k0) * BH);
        #pragma unroll
        for (int i = 0; i < 8; ++i) {
            int e4 = i * 512 + t;
            float4 val = src[e4];
            int elem = e4 * 4;
            int kk = elem >> 5, b0 = elem & 31;   // b0 multiple of 4
            int sw = bswz(b0);                     // rows b0..b0+3: same b0>>2
            T[(b0 + 0) * 512 + (kk ^ sw ^ (0 << 3))] = f2bf(val.x);
            T[(b0 + 1) * 512 + (kk ^ sw ^ (1 << 3))] = f2bf(val.y);
            T[(b0 + 2) * 512 + (kk ^ sw ^ (2 << 3))] = f2bf(val.z);
            T[(b0 + 3) * 512 + (kk ^ sw ^ (3 << 3))] = f2bf(val.w);
        }
        __syncthreads();
        const unsigned short NEGB = f2bf(-1e18f);
        int b = t >> 4;
        int sub = (t & 15) * 8;
        int sw = bswz(b);
        #pragma unroll
        for (int j = 0; j < 4; ++j) {
            int ks = j * 128 + sub;
            size_t gidx = ((size_t)b * SQ + qq) * SQ + k0 + ks;
            us8 tv = *(const us8*)(T + b * 512 + (ks ^ sw));
            us8 pk;
            if (mshift == 2) {
                const int4* mp = (const int4*)((const int*)mask + gidx);
                int4 m0 = mp[0], m1 = mp[1];
                pk[0] = m0.x ? NEGB : (unsigned short)tv[0];
                pk[1] = m0.y ? NEGB : (unsigned short)tv[1];
                pk[2] = m0.z ? NEGB : (unsigned short)tv[2];
                pk[3] = m0.w ? NEGB : (unsigned short)tv[3];
                pk[4] = m1.x ? NEGB : (unsigned short)tv[4];
                pk[5] = m1.y ? NEGB : (unsigned short)tv[5];
                pk[6] = m1.z ? NEGB : (unsigned short)tv[6];
                pk[7] = m1.w ? NEGB : (unsigned short)tv[7];
            } else {
                uint2 mw = *(const uint2*)((const unsigned char*)mask + gidx);
                #pragma unroll
                for (int by = 0; by < 4; ++by) {
                    pk[by]     = ((mw.x >> (by * 8)) & 0xFF) ? NEGB : (unsigned short)tv[by];
                    pk[4 + by] = ((mw.y >> (by * 8)) & 0xFF) ? NEGB : (unsigned short)tv[4 + by];
                }
            }
            __builtin_nontemporal_store(pk, (us8*)(biasT + gidx));
        }
    }
}

// ---------------- K_A: E = exp(QK^T*scale + biasT) bf16, rowinv ----------------
__global__ __launch_bounds__(512, 4) void attn_scores(
    const unsigned short* __restrict__ Qb, const unsigned short* __restrict__ Kb,
    const unsigned short* __restrict__ biasT, float* __restrict__ rowinvG,
    unsigned short* __restrict__ Ebf) {
    extern __shared__ char smem[];   // 2 x 32768 K bufs + 8192 E tile
    __shared__ float rs[32];
    int bid = blockIdx.x;
    int xcd = bid & 7, slot = bid >> 3;
    int b = xcd * 4 + (slot >> 6);
    int q0 = (slot & 63) * 32;
    int tid = threadIdx.x, lane = tid & 63, w = tid >> 6;
    int l15 = lane & 15, lhi = lane >> 4;
    char* Etile = smem + 65536;      // [32 q][128 k] bf16, 16B-XOR swizzled

    const char* Kh = (const char*)(Kb + (size_t)b * SQ * DD);
    size_t qhead = (size_t)b * SQ * DD;
    size_t ehead = (size_t)b * SQ * SQ;

    if (tid < 32) rs[tid] = 0.f;

    bf16x8 qf[2][4];
    #pragma unroll
    for (int qg = 0; qg < 2; ++qg)
        #pragma unroll
        for (int kk = 0; kk < 4; ++kk)
            qf[qg][kk] = *(const bf16x8*)(Qb + qhead +
                           (size_t)(q0 + qg * 16 + l15) * DD + kk * 32 + lhi * 8);

    int srow = tid >> 4;
    int scolb = (tid & 15) * 16;
    #pragma unroll
    for (int p = 0; p < 4; ++p) {
        int row = p * 32 + srow;
        gll16(Kh + (size_t)row * 256 + (scolb ^ ((row & 7) << 4)),
              smem + p * 8192 + tid * 16);
    }
    __syncthreads();

    int eq = tid >> 4;
    int ek = (tid & 15) * 8;
    unsigned short* erow = Ebf + ehead + (size_t)(q0 + eq) * SQ + ek;
    const char* etr = Etile + eq * 256 + ((ek * 2) ^ ((eq & 15) << 4));

    float ps[2] = {0.f, 0.f};
    int kr = w * 16 + l15;
    int ewb = (w * 16 + lhi * 4) * 2;
    #pragma unroll 1
    for (int s = 0; s < 16; ++s) {
        int cur = s & 1;
        if (s < 15) {
            const char* base = Kh + (size_t)(s + 1) * 128 * 256;
            #pragma unroll
            for (int p = 0; p < 4; ++p) {
                int row = p * 32 + srow;
                gll16(base + (size_t)row * 256 + (scolb ^ ((row & 7) << 4)),
                      smem + (cur ^ 1) * 32768 + p * 8192 + tid * 16);
            }
        }
        int kg = s * 128 + w * 16 + lhi * 4;
        ushort4 bv[2];
        #pragma unroll
        for (int qg = 0; qg < 2; ++qg)
            bv[qg] = *(const ushort4*)(biasT + ehead +
                        (size_t)(q0 + qg * 16 + l15) * SQ + kg);
        bf16x8 akk[4];
        #pragma unroll
        for (int kk = 0; kk < 4; ++kk)
            akk[kk] = *(const bf16x8*)(smem + cur * 32768 + kr * 256 +
                         ((kk * 64 + lhi * 16) ^ ((kr & 7) << 4)));
        #pragma unroll
        for (int qg = 0; qg < 2; ++qg) {
            f32x4 acc = {0.f, 0.f, 0.f, 0.f};
            #pragma unroll
            for (int kk = 0; kk < 4; ++kk)
                acc = __builtin_amdgcn_mfma_f32_16x16x32_bf16(akk[kk], qf[qg][kk], acc, 0, 0, 0);
            float u0 = __expf(acc[0] * SCALE + bf2f(bv[qg].x));
            float u1 = __expf(acc[1] * SCALE + bf2f(bv[qg].y));
            float u2 = __expf(acc[2] * SCALE + bf2f(bv[qg].z));
            float u3 = __expf(acc[3] * SCALE + bf2f(bv[qg].w));
            ps[qg] += (u0 + u1) + (u2 + u3);
            ushort4 st;
            st.x = f2bf(u0); st.y = f2bf(u1); st.z = f2bf(u2); st.w = f2bf(u3);
            int q = qg * 16 + l15;
            *(ushort4*)(Etile + q * 256 + (ewb ^ ((q & 15) << 4))) = st;
        }
        __syncthreads();               // E tile ready
        us8 ev = *(const us8*)(etr);
        __builtin_nontemporal_store(ev, (us8*)(erow + s * 128));
        __syncthreads();               // tile readers done; K buf flip safe
    }
    #pragma unroll
    for (int qg = 0; qg < 2; ++qg) {
        float v = ps[qg];
        v += __shfl_xor(v, 16);
        v += __shfl_xor(v, 32);
        if (lane < 16) atomicAdd(&rs[qg * 16 + l15], v);
    }
    __syncthreads();
    if (tid < 32) rowinvG[(size_t)b * SQ + q0 + tid] = 1.0f / rs[tid];
}

// ---------------- K_B: out = (E @ V^T) * rowinv ; attn = E * rowinv ----------------
__global__ __launch_bounds__(512, 4) void attn_pv(
    const unsigned short* __restrict__ Ebf, const unsigned short* __restrict__ VT,
    const float* __restrict__ rowinvG, float* __restrict__ outp,
    float* __restrict__ attnp) {
    extern __shared__ char smem[];   // 2 x (16384 A + 16384 B)
    int bid = blockIdx.x;
    int xcd = bid & 7, slot = bid >> 3;
    int b = xcd * 4 + (slot >> 4);
    int q0 = (slot & 15) * 128;
    int tid = threadIdx.x, lane = tid & 63, w = tid >> 6;
    int wm = w >> 2, wn = w & 3;
    int l15 = lane & 15, lhi = lane >> 4;

    const char* Eh = (const char*)Ebf + ((size_t)b * SQ + q0) * SQ * 2;
    const char* Vh = (const char*)VT + (size_t)b * DD * SQ * 2;

    int srow = tid >> 3;
    int scolb = (tid & 7) * 16;

    int nr = tid >> 4;
    int nk = (tid & 15) * 4;
    float ninv[4];
    #pragma unroll
    for (int p = 0; p < 4; ++p)
        ninv[p] = rowinvG[(size_t)b * SQ + q0 + p * 32 + nr];

    #pragma unroll
    for (int p = 0; p < 2; ++p) {
        int row = p * 64 + srow;
        int sw = scolb ^ ((row & 7) << 4);
        gll16(Eh + (size_t)row * 4096 + sw, smem + p * 8192 + tid * 16);
        gll16(Vh + (size_t)row * 4096 + sw, smem + 16384 + p * 8192 + tid * 16);
    }
    __syncthreads();

    f32x4 acc[4][2] = {};
    #pragma unroll 1
    for (int kt = 0; kt < 32; ++kt) {
        int cur = kt & 1;
        if (kt < 31) {
            size_t koff = (size_t)(kt + 1) * 128;
            char* dst = smem + (cur ^ 1) * 32768;
            #pragma unroll
            for (int p = 0; p < 2; ++p) {
                int row = p * 64 + srow;
                int sw = scolb ^ ((row & 7) << 4);
                gll16(Eh + (size_t)row * 4096 + koff + sw, dst + p * 8192 + tid * 16);
                gll16(Vh + (size_t)row * 4096 + koff + sw, dst + 16384 + p * 8192 + tid * 16);
            }
        }
        const char* Ab = smem + cur * 32768;
        const char* Bb = Ab + 16384;
        bf16x8 af[4][2], bf[2][2];
        #pragma unroll
        for (int m = 0; m < 4; ++m) {
            int qr = wm * 64 + m * 16 + l15;
            #pragma unroll
            for (int ks = 0; ks < 2; ++ks)
                af[m][ks] = *(const bf16x8*)(Ab + qr * 128 +
                              ((ks * 64 + lhi * 16) ^ ((qr & 7) << 4)));
        }
        #pragma unroll
        for (int n = 0; n < 2; ++n) {
            int dr = wn * 32 + n * 16 + l15;
            #pragma unroll
            for (int ks = 0; ks < 2; ++ks)
                bf[n][ks] = *(const bf16x8*)(Bb + dr * 128 +
                              ((ks * 64 + lhi * 16) ^ ((dr & 7) << 4)));
        }
        #pragma unroll
        for (int m = 0; m < 4; ++m)
            #pragma unroll
            for (int n = 0; n < 2; ++n)
                #pragma unroll
                for (int ks = 0; ks < 2; ++ks)
                    acc[m][n] = __builtin_amdgcn_mfma_f32_16x16x32_bf16(
                                  af[m][ks], bf[n][ks], acc[m][n], 0, 0, 0);
        #pragma unroll
        for (int p = 0; p < 4; ++p) {
            int row = p * 32 + nr;
            ushort4 e = *(const ushort4*)(Ab + row * 128 + ((nk * 2) ^ ((row & 7) << 4)));
            f32x4 o;
            o[0] = bf2f(e.x) * ninv[p];
            o[1] = bf2f(e.y) * ninv[p];
            o[2] = bf2f(e.z) * ninv[p];
            o[3] = bf2f(e.w) * ninv[p];
            __builtin_nontemporal_store(o,
                (f32x4*)(attnp + ((size_t)b * SQ + q0 + row) * SQ + kt * 64 + nk));
        }
        __syncthreads();
    }
    #pragma unroll
    for (int m = 0; m < 4; ++m) {
        #pragma unroll
        for (int r = 0; r < 4; ++r) {
            int q = q0 + wm * 64 + m * 16 + lhi * 4 + r;
            float inv = rowinvG[(size_t)b * SQ + q];
            #pragma unroll
            for (int n = 0; n < 2; ++n)
                __builtin_nontemporal_store(acc[m][n][r] * inv,
                    outp + ((size_t)b * SQ + q) * DD + wn * 32 + n * 16 + l15);
        }
    }
}

// ---------------- fallback path (ws too small for Ebf): f32-E kernels ----------------
__global__ void cvt_qk(const float* __restrict__ q, const float* __restrict__ k,
                       unsigned short* __restrict__ qb, unsigned short* __restrict__ kb) {
    const size_t n4 = (size_t)BH * SQ * DD / 4;
    size_t i = (size_t)blockIdx.x * blockDim.x + threadIdx.x;
    size_t stride = (size_t)gridDim.x * blockDim.x;
    for (; i < 2 * n4; i += stride) {
        const float4* src = (i < n4) ? (const float4*)q : (const float4*)k;
        unsigned short* dst = (i < n4) ? qb : kb;
        size_t j = (i < n4) ? i : i - n4;
        float4 v = src[j];
        ushort4 o;
        o.x = f2bf(v.x); o.y = f2bf(v.y); o.z = f2bf(v.z); o.w = f2bf(v.w);
        *(ushort4*)(dst + j * 4) = o;
    }
}

__global__ void cvt_vt(const float* __restrict__ v, unsigned short* __restrict__ vt) {
    __shared__ unsigned short tile[128 * VT_LD];
    int b = blockIdx.x >> 4;
    int kt = blockIdx.x & 15;
    size_t vbase = ((size_t)b * SQ + (size_t)kt * 128) * DD;
    int t = threadIdx.x;   // 512
    for (int i = 0; i < 8; ++i) {
        size_t fi = (size_t)i * 2048 + (size_t)t * 4;
        float4 val = *(const float4*)(v + vbase + fi);
        int kk = (int)(fi >> 7);
        int d0 = (int)(fi & 127);
        tile[(d0 + 0) * VT_LD + kk] = f2bf(val.x);
        tile[(d0 + 1) * VT_LD + kk] = f2bf(val.y);
        tile[(d0 + 2) * VT_LD + kk] = f2bf(val.z);
        tile[(d0 + 3) * VT_LD + kk] = f2bf(val.w);
    }
    __syncthreads();
    int d = t >> 2, ks = (t & 3) * 32;
    size_t obase = (size_t)b * (DD * SQ) + (size_t)d * SQ + (size_t)kt * 128 + ks;
    const unsigned short* row = tile + d * VT_LD + ks;
    #pragma unroll
    for (int j = 0; j < 4; ++j)
        *(int4*)(vt + obase + j * 8) = *(const int4*)(row + j * 8);
}

__global__ void xform_bias(const float* __restrict__ bias, const void* __restrict__ mask,
                           unsigned short* __restrict__ biasT) {
    __shared__ unsigned short T[32][XB_LD];
    int q = blockIdx.x >> 2, kc = blockIdx.x & 3;
    int k0 = kc * 512;
    int t = threadIdx.x;   // 256
    int mshift = mask_byte_shift(mask);
    const float4* src = (const float4*)(bias + ((size_t)q * SQ + k0) * BH);
    #pragma unroll
    for (int i = 0; i < 16; ++i) {
        int e4 = i * 256 + t;
        float4 v = src[e4];
        int elem = e4 * 4;
        int k = elem >> 5, b0 = elem & 31;
        T[b0 + 0][k] = f2bf(v.x); T[b0 + 1][k] = f2bf(v.y);
        T[b0 + 2][k] = f2bf(v.z); T[b0 + 3][k] = f2bf(v.w);
    }
    __syncthreads();
    const unsigned short NEGB = f2bf(-1e18f);
    int b = t >> 3;
    int toff = (t & 7) * 8;
    #pragma unroll
    for (int j = 0; j < 8; ++j) {
        int ks = j * 64 + toff;
        size_t gidx = ((size_t)b * SQ + q) * SQ + k0 + ks;
        unsigned short o[8];
        if (mshift == 2) {
            const int4* mp = (const int4*)((const int*)mask + gidx);
            int4 m0 = mp[0], m1 = mp[1];
            o[0] = m0.x ? NEGB : T[b][ks + 0];
            o[1] = m0.y ? NEGB : T[b][ks + 1];
            o[2] = m0.z ? NEGB : T[b][ks + 2];
            o[3] = m0.w ? NEGB : T[b][ks + 3];
            o[4] = m1.x ? NEGB : T[b][ks + 4];
            o[5] = m1.y ? NEGB : T[b][ks + 5];
            o[6] = m1.z ? NEGB : T[b][ks + 6];
            o[7] = m1.w ? NEGB : T[b][ks + 7];
        } else {
            uint2 mw = *(const uint2*)((const unsigned char*)mask + gidx);
            #pragma unroll
            for (int by = 0; by < 4; ++by) {
                o[by]     = ((mw.x >> (by * 8)) & 0xFF) ? NEGB : T[b][ks + by];
                o[4 + by] = ((mw.y >> (by * 8)) & 0xFF) ? NEGB : T[b][ks + 4 + by];
            }
        }
        us8 pk;
        #pragma unroll
        for (int c = 0; c < 8; ++c) pk[c] = o[c];
        __builtin_nontemporal_store(pk, (us8*)(biasT + gidx));
    }
}

__global__ __launch_bounds__(512, 4) void attn_scores_f32(
    const unsigned short* __restrict__ Qb, const unsigned short* __restrict__ Kb,
    const unsigned short* __restrict__ biasT, float* __restrict__ rowinvG,
    float* __restrict__ Ef) {
    __shared__ float rs[32];
    int b = blockIdx.x >> 6, qt = blockIdx.x & 63;
    int q0 = qt * 32;
    int tid = threadIdx.x, lane = tid & 63, w = tid >> 6;
    int l15 = lane & 15, lhi = lane >> 4;
    if (tid < 32) rs[tid] = 0.f;
    __syncthreads();
    size_t headQK = (size_t)b * (SQ * DD);
    size_t ebase = (size_t)b * SQ * SQ;
    bf16x8 qf[2][4];
    #pragma unroll
    for (int qg = 0; qg < 2; ++qg)
        #pragma unroll
        for (int ds = 0; ds < 4; ++ds)
            qf[qg][ds] = *(const bf16x8*)(Qb + headQK +
                           (size_t)(q0 + qg * 16 + l15) * DD + ds * 32 + lhi * 8);
    float ps[2] = {0.f, 0.f};
    #pragma unroll 1
    for (int kt = 0; kt < 16; ++kt) {
        int kbase = w * 256 + kt * 16;
        bf16x8 kf[4];
        #pragma unroll
        for (int ds = 0; ds < 4; ++ds)
            kf[ds] = *(const bf16x8*)(Kb + headQK +
                       (size_t)(kbase + l15) * DD + ds * 32 + lhi * 8);
        #pragma unroll
        for (int qg = 0; qg < 2; ++qg) {
            f32x4 acc = {0.f, 0.f, 0.f, 0.f};
            #pragma unroll
            for (int ds = 0; ds < 4; ++ds)
                acc = __builtin_amdgcn_mfma_f32_16x16x32_bf16(kf[ds], qf[qg][ds], acc, 0, 0, 0);
            int q = q0 + qg * 16 + l15;
            int k = kbase + lhi * 4;
            size_t eidx = ebase + (size_t)q * SQ + k;
            ushort4 bv = *(const ushort4*)(biasT + eidx);
            float u0 = __expf(acc[0] * SCALE + bf2f(bv.x));
            float u1 = __expf(acc[1] * SCALE + bf2f(bv.y));
            float u2 = __expf(acc[2] * SCALE + bf2f(bv.z));
            float u3 = __expf(acc[3] * SCALE + bf2f(bv.w));
            ps[qg] += (u0 + u1) + (u2 + u3);
            float4 st = {u0, u1, u2, u3};
            *(float4*)(Ef + eidx) = st;
        }
    }
    #pragma unroll
    for (int qg = 0; qg < 2; ++qg) {
        float v = ps[qg];
        v += __shfl_xor(v, 16);
        v += __shfl_xor(v, 32);
        if (lane < 16) atomicAdd(&rs[qg * 16 + l15], v);
    }
    __syncthreads();
    if (tid < 32) rowinvG[(size_t)b * SQ + q0 + tid] = 1.0f / rs[tid];
}

__global__ __launch_bounds__(512, 4) void attn_pv_f32(
    const unsigned short* __restrict__ VT, const float* __restrict__ rowinvG,
    float* __restrict__ Ef, float* __restrict__ outp, float* __restrict__ attnp) {
    int b = blockIdx.x >> 6, qt = blockIdx.x & 63;
    int q0 = qt * 32;
    int tid = threadIdx.x, lane = tid & 63, w = tid >> 6;
    int qg = w >> 2, ds = w & 3;
    int l15 = lane & 15, lhi = lane >> 4;
    size_t ebase = (size_t)b * SQ * SQ;
    size_t vbase = (size_t)b * (DD * SQ);
    f32x4 acc[2] = {{0.f,0.f,0.f,0.f},{0.f,0.f,0.f,0.f}};
    const size_t arow = ebase + (size_t)(q0 + qg * 16 + l15) * SQ;
    #pragma unroll 2
    for (int kt = 0; kt < 64; ++kt) {
        int k = kt * 32 + lhi * 8;
        float4 a0 = *(const float4*)(Ef + arow + k);
        float4 a1 = *(const float4*)(Ef + arow + k + 4);
        bf16x8 af;
        af[0] = (short)f2bf(a0.x); af[1] = (short)f2bf(a0.y);
        af[2] = (short)f2bf(a0.z); af[3] = (short)f2bf(a0.w);
        af[4] = (short)f2bf(a1.x); af[5] = (short)f2bf(a1.y);
        af[6] = (short)f2bf(a1.z); af[7] = (short)f2bf(a1.w);
        #pragma unroll
        for (int m = 0; m < 2; ++m) {
            bf16x8 bfr = *(const bf16x8*)(VT + vbase +
                           (size_t)(ds * 32 + m * 16 + l15) * SQ + k);
            acc[m] = __builtin_amdgcn_mfma_f32_16x16x32_bf16(af, bfr, acc[m], 0, 0, 0);
        }
    }
    #pragma unroll
    for (int m = 0; m < 2; ++m)
        #pragma unroll
        for (int r = 0; r < 4; ++r) {
            int q = q0 + qg * 16 + lhi * 4 + r;
            float inv = rowinvG[(size_t)b * SQ + q];
            outp[((size_t)b * SQ + q) * DD + ds * 32 + m * 16 + l15] = acc[m][r] * inv;
        }
    __syncthreads();
    int row = tid >> 4;
    int coff = (tid & 15) * 4;
    float inv = rowinvG[(size_t)b * SQ + q0 + row];
    size_t rbase = ebase + (size_t)(q0 + row) * SQ;
    #pragma unroll 4
    for (int it = 0; it < 32; ++it) {
        int k = it * 64 + coff;
        float4 u = *(const float4*)(Ef + rbase + k);
        u.x *= inv; u.y *= inv; u.z *= inv; u.w *= inv;
        *(float4*)(attnp + rbase + k) = u;
    }
}

// ---------------- naive last-resort ----------------
__global__ void attn_naive(const float* __restrict__ Q, const float* __restrict__ K,
                           const float* __restrict__ V, const float* __restrict__ bias,
                           const void* __restrict__ mask,
                           float* __restrict__ outp, float* __restrict__ attnp) {
    __shared__ float qrow[DD];
    __shared__ float prow[SQ];
    __shared__ float red[4];
    int b = blockIdx.x >> 11;
    int q = blockIdx.x & 2047;
    int tid = threadIdx.x;
    int mshift = mask_byte_shift(mask);
    const unsigned char* M = (const unsigned char*)mask;
    if (tid < DD) qrow[tid] = Q[((size_t)b * SQ + q) * DD + tid];
    __syncthreads();
    float lsum = 0.f;
    for (int k = tid; k < SQ; k += 256) {
        float s = 0.f;
        const float* kr = K + ((size_t)b * SQ + k) * DD;
        for (int d = 0; d < DD; ++d) s += qrow[d] * kr[d];
        s = s * SCALE + bias[((size_t)q * SQ + k) * BH + b];
        size_t midx = ((size_t)b * SQ + q) * SQ + k;
        float p = (M[midx << mshift] != 0) ? 0.f : __expf(s);
        prow[k] = p; lsum += p;
    }
    lsum += __shfl_xor(lsum, 1);  lsum += __shfl_xor(lsum, 2);
    lsum += __shfl_xor(lsum, 4);  lsum += __shfl_xor(lsum, 8);
    lsum += __shfl_xor(lsum, 16); lsum += __shfl_xor(lsum, 32);
    if ((tid & 63) == 0) red[tid >> 6] = lsum;
    __syncthreads();
    float inv = 1.0f / (red[0] + red[1] + red[2] + red[3]);
    for (int k = tid; k < SQ; k += 256) {
        float p = prow[k] * inv;
        prow[k] = p;
        attnp[((size_t)b * SQ + q) * SQ + k] = p;
    }
    __syncthreads();
    if (tid < DD) {
        float o = 0.f;
        for (int k = 0; k < SQ; ++k) o += prow[k] * V[((size_t)b * SQ + k) * DD + tid];
        outp[((size_t)b * SQ + q) * DD + tid] = o;
    }
}

extern "C" void kernel_launch(void* const* d_in, const int* in_sizes, int n_in,
                              void* d_out, int out_size, void* d_ws, size_t ws_size,
                              hipStream_t stream) {
    const float* Q = (const float*)d_in[0];
    const float* K = (const float*)d_in[1];
    const float* V = (const float*)d_in[2];
    const float* bias = (const float*)d_in[3];
    const void* mask = d_in[4];
    float* outp = (float*)d_out;
    float* attnp = outp + (size_t)BH * SQ * DD;

    const size_t tsz = (size_t)BH * SQ * DD;          // 8388608
    const size_t biasN = (size_t)BH * SQ * SQ;        // 134217728
    const size_t cvtB = tsz * 2 * 3;                  // 48 MB
    const size_t needF32 = cvtB + biasN * 2 + (size_t)BH * SQ * 4;   // ~319 MB
    const size_t needBF = needF32 + biasN * 2;                        // ~587 MB

    if (ws_size >= cvtB) {
        char* p = (char*)d_ws;
        unsigned short* Qbf = (unsigned short*)p;          p += tsz * 2;
        unsigned short* Kbf = (unsigned short*)p;          p += tsz * 2;
        unsigned short* VTp = (unsigned short*)p;          p += tsz * 2;
        if (ws_size >= needBF) {
            unsigned short* biasT = (unsigned short*)p;    p += biasN * 2;
            float* rowinvG = (float*)p;                    p += (size_t)BH * SQ * 4;
            unsigned short* Ebf = (unsigned short*)p;
            prep_all<<<9216, 512, 0, stream>>>(Q, K, V, bias, mask, Qbf, Kbf, VTp, biasT);
            hipError_t e1 = hipFuncSetAttribute((const void*)attn_scores,
                                hipFuncAttributeMaxDynamicSharedMemorySize, 73728);
            hipError_t e2 = hipFuncSetAttribute((const void*)attn_pv,
                                hipFuncAttributeMaxDynamicSharedMemorySize, 65536);
            (void)e1; (void)e2;
            attn_scores<<<2048, 512, 73728, stream>>>(Qbf, Kbf, biasT, rowinvG, Ebf);
            attn_pv<<<512, 512, 65536, stream>>>(Ebf, VTp, rowinvG, outp, attnp);
        } else if (ws_size >= needF32) {
            unsigned short* biasT = (unsigned short*)p;    p += biasN * 2;
            float* rowinvG = (float*)p;                    p += (size_t)BH * SQ * 4;
            cvt_qk<<<4096, 256, 0, stream>>>(Q, K, Qbf, Kbf);
            cvt_vt<<<512, 512, 0, stream>>>(V, VTp);
            xform_bias<<<8192, 256, 0, stream>>>(bias, mask, biasT);
            attn_scores_f32<<<2048, 512, 0, stream>>>(Qbf, Kbf, biasT, rowinvG, attnp);
            attn_pv_f32<<<2048, 512, 0, stream>>>(VTp, rowinvG, attnp, outp, attnp);
        } else {
            attn_naive<<<BH * SQ, 256, 0, stream>>>(Q, K, V, bias, mask, outp, attnp);
        }
    } else {
        attn_naive<<<BH * SQ, 256, 0, stream>>>(Q, K, V, bias, mask, outp, attnp);
    }
}

// Round 16
// 637.208 us; speedup vs baseline: 1.0576x; 1.0576x over previous
//
#include <hip/hip_runtime.h>
#include <hip/hip_bf16.h>

#define BH 32
#define SQ 2048
#define DD 128
#define SCALE 0.08838834764831845f

typedef short bf16x8 __attribute__((ext_vector_type(8)));
typedef unsigned short us8 __attribute__((ext_vector_type(8)));
typedef float f32x4 __attribute__((ext_vector_type(4)));

typedef __attribute__((address_space(1))) const unsigned gu32;
typedef __attribute__((address_space(3))) unsigned lu32;
__device__ __forceinline__ void gll16(const void* g, void* l) {
    __builtin_amdgcn_global_load_lds((gu32*)g, (lu32*)l, 16, 0, 0);
}

__device__ __forceinline__ unsigned short f2bf(float f) {
    unsigned u = __float_as_uint(f);
    u = u + 0x7FFFu + ((u >> 16) & 1u);   // RNE
    return (unsigned short)(u >> 16);
}
__device__ __forceinline__ float bf2f(unsigned short h) {
    return __uint_as_float(((unsigned)h) << 16);
}

// mask elem width detect: int32 {0,1} has zero bytes at off%4!=0
__device__ __forceinline__ int mask_byte_shift(const void* m) {
    const unsigned char* p = (const unsigned char*)m;
    int l = threadIdx.x & 63;
    unsigned char v = p[l];
    unsigned long long nz = __ballot(((l & 3) != 0) && (v != 0));
    return (nz != 0ull) ? 0 : 2;
}

// bias-transpose LDS swizzle: 8-block-preserving XOR, conflict-free both phases
__device__ __forceinline__ int bswz(int row) {
    return ((((row) >> 2) & 7) ^ ((row) & 3)) << 3;
}

// ---------------- merged prep: VT transpose | QK cvt | bias+mask xform ----------------
#define VT_LD 136
#define XB_LD 522
__global__ __launch_bounds__(512) void prep_all(
    const float* __restrict__ q, const float* __restrict__ k, const float* __restrict__ v,
    const float* __restrict__ bias, const void* __restrict__ mask,
    unsigned short* __restrict__ qb, unsigned short* __restrict__ kb,
    unsigned short* __restrict__ vt, unsigned short* __restrict__ biasT) {
    __shared__ char lds[128 * VT_LD * 2];
    int t = threadIdx.x;   // 512
    int bid = blockIdx.x;
    if (bid < 512) {
        // ---- V transpose tile ----
        unsigned short* tile = (unsigned short*)lds;
        int b = bid >> 4;
        int kt = bid & 15;
        size_t vbase = ((size_t)b * SQ + (size_t)kt * 128) * DD;
        for (int i = 0; i < 8; ++i) {
            size_t fi = (size_t)i * 2048 + (size_t)t * 4;
            float4 val = *(const float4*)(v + vbase + fi);
            int kk = (int)(fi >> 7);
            int d0 = (int)(fi & 127);
            tile[(d0 + 0) * VT_LD + kk] = f2bf(val.x);
            tile[(d0 + 1) * VT_LD + kk] = f2bf(val.y);
            tile[(d0 + 2) * VT_LD + kk] = f2bf(val.z);
            tile[(d0 + 3) * VT_LD + kk] = f2bf(val.w);
        }
        __syncthreads();
        int d = t >> 2, ks = (t & 3) * 32;
        size_t obase = (size_t)b * (DD * SQ) + (size_t)d * SQ + (size_t)kt * 128 + ks;
        const unsigned short* row = tile + d * VT_LD + ks;
        #pragma unroll
        for (int j = 0; j < 4; ++j)
            *(int4*)(vt + obase + j * 8) = *(const int4*)(row + j * 8);
    } else if (bid < 1024) {
        // ---- Q,K convert (grid-stride over 512 blocks) ----
        const size_t n4 = (size_t)BH * SQ * DD / 4;
        size_t i = (size_t)(bid - 512) * 512 + t;
        const size_t stride = 512 * 512;
        for (; i < 2 * n4; i += stride) {
            const float4* src = (i < n4) ? (const float4*)q : (const float4*)k;
            unsigned short* dst = (i < n4) ? qb : kb;
            size_t j = (i < n4) ? i : i - n4;
            float4 val = src[j];
            ushort4 o;
            o.x = f2bf(val.x); o.y = f2bf(val.y); o.z = f2bf(val.z); o.w = f2bf(val.w);
            *(ushort4*)(dst + j * 4) = o;
        }
    } else {
        // ---- biasT[b][q][k] = mask ? -1e18 : bias (bf16) ----
        unsigned short* T = (unsigned short*)lds;
        int xb = bid - 1024;                 // 0..8191
        int qq = xb >> 2, kc = xb & 3;
        int k0 = kc * 512;
        int mshift = mask_byte_shift(mask);
        const float4* src = (const float4*)(bias + ((size_t)qq * SQ + k0) * BH);
        #pragma unroll
        for (int i = 0; i < 8; ++i) {
            int e4 = i * 512 + t;
            float4 val = src[e4];
            int elem = e4 * 4;
            int kk = elem >> 5, b0 = elem & 31;
            int sw = bswz(b0);
            T[(b0 + 0) * 512 + (kk ^ sw ^ (0 << 3))] = f2bf(val.x);
            T[(b0 + 1) * 512 + (kk ^ sw ^ (1 << 3))] = f2bf(val.y);
            T[(b0 + 2) * 512 + (kk ^ sw ^ (2 << 3))] = f2bf(val.z);
            T[(b0 + 3) * 512 + (kk ^ sw ^ (3 << 3))] = f2bf(val.w);
        }
        __syncthreads();
        const unsigned short NEGB = f2bf(-1e18f);
        int b = t >> 4;
        int sub = (t & 15) * 8;
        int sw = bswz(b);
        #pragma unroll
        for (int j = 0; j < 4; ++j) {
            int ks = j * 128 + sub;
            size_t gidx = ((size_t)b * SQ + qq) * SQ + k0 + ks;
            us8 tv = *(const us8*)(T + b * 512 + (ks ^ sw));
            us8 pk;
            if (mshift == 2) {
                const int4* mp = (const int4*)((const int*)mask + gidx);
                int4 m0 = mp[0], m1 = mp[1];
                pk[0] = m0.x ? NEGB : (unsigned short)tv[0];
                pk[1] = m0.y ? NEGB : (unsigned short)tv[1];
                pk[2] = m0.z ? NEGB : (unsigned short)tv[2];
                pk[3] = m0.w ? NEGB : (unsigned short)tv[3];
                pk[4] = m1.x ? NEGB : (unsigned short)tv[4];
                pk[5] = m1.y ? NEGB : (unsigned short)tv[5];
                pk[6] = m1.z ? NEGB : (unsigned short)tv[6];
                pk[7] = m1.w ? NEGB : (unsigned short)tv[7];
            } else {
                uint2 mw = *(const uint2*)((const unsigned char*)mask + gidx);
                #pragma unroll
                for (int by = 0; by < 4; ++by) {
                    pk[by]     = ((mw.x >> (by * 8)) & 0xFF) ? NEGB : (unsigned short)tv[by];
                    pk[4 + by] = ((mw.y >> (by * 8)) & 0xFF) ? NEGB : (unsigned short)tv[4 + by];
                }
            }
            __builtin_nontemporal_store(pk, (us8*)(biasT + gidx));
        }
    }
}

// ---------------- K_A: E = exp(QK^T*scale + biasT) bf16, rowinv ----------------
// 64q tile: 16 MFMA per wave per staging round (2x density of 32q). grid 1024.
// LDS: 2x32KB K bufs + 16KB E tile = 80KB exact -> 2 blocks/CU. rs[64] reuses
// the E-tile region after the k-loop (keeps dyn LDS at 80KB).
__global__ __launch_bounds__(512, 2) void attn_scores(
    const unsigned short* __restrict__ Qb, const unsigned short* __restrict__ Kb,
    const unsigned short* __restrict__ biasT, float* __restrict__ rowinvG,
    unsigned short* __restrict__ Ebf) {
    extern __shared__ char smem[];   // 65536 K bufs + 16384 E tile = 81920
    int bid = blockIdx.x;
    int xcd = bid & 7, slot = bid >> 3;          // slot 0..127
    int b = xcd * 4 + (slot >> 5);
    int q0 = (slot & 31) * 64;
    int tid = threadIdx.x, lane = tid & 63, w = tid >> 6;
    int l15 = lane & 15, lhi = lane >> 4;
    char* Etile = smem + 65536;      // [64 q][128 k] bf16, 16B-XOR swizzled

    const char* Kh = (const char*)(Kb + (size_t)b * SQ * DD);
    size_t qhead = (size_t)b * SQ * DD;
    size_t ehead = (size_t)b * SQ * SQ;

    bf16x8 qf[4][4];
    #pragma unroll
    for (int qg = 0; qg < 4; ++qg)
        #pragma unroll
        for (int kk = 0; kk < 4; ++kk)
            qf[qg][kk] = *(const bf16x8*)(Qb + qhead +
                           (size_t)(q0 + qg * 16 + l15) * DD + kk * 32 + lhi * 8);

    int srow = tid >> 4;
    int scolb = (tid & 15) * 16;
    #pragma unroll
    for (int p = 0; p < 4; ++p) {
        int row = p * 32 + srow;
        gll16(Kh + (size_t)row * 256 + (scolb ^ ((row & 7) << 4)),
              smem + p * 8192 + tid * 16);
    }
    __syncthreads();

    // E-store assignment: thread t -> q-row (t>>3), two 8-elem chunks (t&7)*8, +64
    int eq = tid >> 3;
    int ek = (tid & 7) * 8;
    unsigned short* erow = Ebf + ehead + (size_t)(q0 + eq) * SQ;
    const char* etr0 = Etile + eq * 256 + ((ek * 2) ^ ((eq & 15) << 4));
    const char* etr1 = Etile + eq * 256 + (((ek + 64) * 2) ^ ((eq & 15) << 4));

    float ps[4] = {0.f, 0.f, 0.f, 0.f};
    int kr = w * 16 + l15;
    int ewb = (w * 16 + lhi * 4) * 2;   // byte col of this lane's 4-k piece
    #pragma unroll 1
    for (int s = 0; s < 16; ++s) {
        int cur = s & 1;
        if (s < 15) {
            const char* base = Kh + (size_t)(s + 1) * 128 * 256;
            #pragma unroll
            for (int p = 0; p < 4; ++p) {
                int row = p * 32 + srow;
                gll16(base + (size_t)row * 256 + (scolb ^ ((row & 7) << 4)),
                      smem + (cur ^ 1) * 32768 + p * 8192 + tid * 16);
            }
        }
        int kg = s * 128 + w * 16 + lhi * 4;
        bf16x8 akk[4];
        #pragma unroll
        for (int kk = 0; kk < 4; ++kk)
            akk[kk] = *(const bf16x8*)(smem + cur * 32768 + kr * 256 +
                         ((kk * 64 + lhi * 16) ^ ((kr & 7) << 4)));
        #pragma unroll
        for (int qg = 0; qg < 4; ++qg) {
            ushort4 bv = *(const ushort4*)(biasT + ehead +
                           (size_t)(q0 + qg * 16 + l15) * SQ + kg);
            f32x4 acc = {0.f, 0.f, 0.f, 0.f};
            #pragma unroll
            for (int kk = 0; kk < 4; ++kk)
                acc = __builtin_amdgcn_mfma_f32_16x16x32_bf16(akk[kk], qf[qg][kk], acc, 0, 0, 0);
            float u0 = __expf(acc[0] * SCALE + bf2f(bv.x));
            float u1 = __expf(acc[1] * SCALE + bf2f(bv.y));
            float u2 = __expf(acc[2] * SCALE + bf2f(bv.z));
            float u3 = __expf(acc[3] * SCALE + bf2f(bv.w));
            ps[qg] += (u0 + u1) + (u2 + u3);
            ushort4 st;
            st.x = f2bf(u0); st.y = f2bf(u1); st.z = f2bf(u2); st.w = f2bf(u3);
            int qrow = qg * 16 + l15;
            *(ushort4*)(Etile + qrow * 256 + (ewb ^ ((qrow & 15) << 4))) = st;
        }
        __syncthreads();               // E tile ready
        us8 ev0 = *(const us8*)(etr0);
        us8 ev1 = *(const us8*)(etr1);
        __builtin_nontemporal_store(ev0, (us8*)(erow + s * 128 + ek));
        __builtin_nontemporal_store(ev1, (us8*)(erow + s * 128 + ek + 64));
        __syncthreads();               // tile readers done; K buf flip safe
    }
    // rowsum: reuse E-tile region for rs[64] (E tile dead after the loop)
    float* rs = (float*)(smem + 65536);
    if (tid < 64) rs[tid] = 0.f;
    __syncthreads();
    #pragma unroll
    for (int qg = 0; qg < 4; ++qg) {
        float vv = ps[qg];
        vv += __shfl_xor(vv, 16);
        vv += __shfl_xor(vv, 32);
        if (lane < 16) atomicAdd(&rs[qg * 16 + l15], vv);
    }
    __syncthreads();
    if (tid < 64) rowinvG[(size_t)b * SQ + q0 + tid] = 1.0f / rs[tid];
}

// ---------------- K_B: out = (E @ V^T) * rowinv ; attn = E * rowinv ----------------
__global__ __launch_bounds__(512, 4) void attn_pv(
    const unsigned short* __restrict__ Ebf, const unsigned short* __restrict__ VT,
    const float* __restrict__ rowinvG, float* __restrict__ outp,
    float* __restrict__ attnp) {
    extern __shared__ char smem[];   // 2 x (16384 A + 16384 B)
    int bid = blockIdx.x;
    int xcd = bid & 7, slot = bid >> 3;
    int b = xcd * 4 + (slot >> 4);
    int q0 = (slot & 15) * 128;
    int tid = threadIdx.x, lane = tid & 63, w = tid >> 6;
    int wm = w >> 2, wn = w & 3;
    int l15 = lane & 15, lhi = lane >> 4;

    const char* Eh = (const char*)Ebf + ((size_t)b * SQ + q0) * SQ * 2;
    const char* Vh = (const char*)VT + (size_t)b * DD * SQ * 2;

    int srow = tid >> 3;
    int scolb = (tid & 7) * 16;

    int nr = tid >> 4;
    int nk = (tid & 15) * 4;
    float ninv[4];
    #pragma unroll
    for (int p = 0; p < 4; ++p)
        ninv[p] = rowinvG[(size_t)b * SQ + q0 + p * 32 + nr];

    #pragma unroll
    for (int p = 0; p < 2; ++p) {
        int row = p * 64 + srow;
        int sw = scolb ^ ((row & 7) << 4);
        gll16(Eh + (size_t)row * 4096 + sw, smem + p * 8192 + tid * 16);
        gll16(Vh + (size_t)row * 4096 + sw, smem + 16384 + p * 8192 + tid * 16);
    }
    __syncthreads();

    f32x4 acc[4][2] = {};
    #pragma unroll 1
    for (int kt = 0; kt < 32; ++kt) {
        int cur = kt & 1;
        if (kt < 31) {
            size_t koff = (size_t)(kt + 1) * 128;
            char* dst = smem + (cur ^ 1) * 32768;
            #pragma unroll
            for (int p = 0; p < 2; ++p) {
                int row = p * 64 + srow;
                int sw = scolb ^ ((row & 7) << 4);
                gll16(Eh + (size_t)row * 4096 + koff + sw, dst + p * 8192 + tid * 16);
                gll16(Vh + (size_t)row * 4096 + koff + sw, dst + 16384 + p * 8192 + tid * 16);
            }
        }
        const char* Ab = smem + cur * 32768;
        const char* Bb = Ab + 16384;
        bf16x8 af[4][2], bf[2][2];
        #pragma unroll
        for (int m = 0; m < 4; ++m) {
            int qr = wm * 64 + m * 16 + l15;
            #pragma unroll
            for (int ks = 0; ks < 2; ++ks)
                af[m][ks] = *(const bf16x8*)(Ab + qr * 128 +
                              ((ks * 64 + lhi * 16) ^ ((qr & 7) << 4)));
        }
        #pragma unroll
        for (int n = 0; n < 2; ++n) {
            int dr = wn * 32 + n * 16 + l15;
            #pragma unroll
            for (int ks = 0; ks < 2; ++ks)
                bf[n][ks] = *(const bf16x8*)(Bb + dr * 128 +
                              ((ks * 64 + lhi * 16) ^ ((dr & 7) << 4)));
        }
        #pragma unroll
        for (int m = 0; m < 4; ++m)
            #pragma unroll
            for (int n = 0; n < 2; ++n)
                #pragma unroll
                for (int ks = 0; ks < 2; ++ks)
                    acc[m][n] = __builtin_amdgcn_mfma_f32_16x16x32_bf16(
                                  af[m][ks], bf[n][ks], acc[m][n], 0, 0, 0);
        #pragma unroll
        for (int p = 0; p < 4; ++p) {
            int row = p * 32 + nr;
            ushort4 e = *(const ushort4*)(Ab + row * 128 + ((nk * 2) ^ ((row & 7) << 4)));
            f32x4 o;
            o[0] = bf2f(e.x) * ninv[p];
            o[1] = bf2f(e.y) * ninv[p];
            o[2] = bf2f(e.z) * ninv[p];
            o[3] = bf2f(e.w) * ninv[p];
            __builtin_nontemporal_store(o,
                (f32x4*)(attnp + ((size_t)b * SQ + q0 + row) * SQ + kt * 64 + nk));
        }
        __syncthreads();
    }
    #pragma unroll
    for (int m = 0; m < 4; ++m) {
        #pragma unroll
        for (int r = 0; r < 4; ++r) {
            int q = q0 + wm * 64 + m * 16 + lhi * 4 + r;
            float inv = rowinvG[(size_t)b * SQ + q];
            #pragma unroll
            for (int n = 0; n < 2; ++n)
                __builtin_nontemporal_store(acc[m][n][r] * inv,
                    outp + ((size_t)b * SQ + q) * DD + wn * 32 + n * 16 + l15);
        }
    }
}

// ---------------- fallback path (ws too small for Ebf): f32-E kernels ----------------
__global__ void cvt_qk(const float* __restrict__ q, const float* __restrict__ k,
                       unsigned short* __restrict__ qb, unsigned short* __restrict__ kb) {
    const size_t n4 = (size_t)BH * SQ * DD / 4;
    size_t i = (size_t)blockIdx.x * blockDim.x + threadIdx.x;
    size_t stride = (size_t)gridDim.x * blockDim.x;
    for (; i < 2 * n4; i += stride) {
        const float4* src = (i < n4) ? (const float4*)q : (const float4*)k;
        unsigned short* dst = (i < n4) ? qb : kb;
        size_t j = (i < n4) ? i : i - n4;
        float4 v = src[j];
        ushort4 o;
        o.x = f2bf(v.x); o.y = f2bf(v.y); o.z = f2bf(v.z); o.w = f2bf(v.w);
        *(ushort4*)(dst + j * 4) = o;
    }
}

__global__ void cvt_vt(const float* __restrict__ v, unsigned short* __restrict__ vt) {
    __shared__ unsigned short tile[128 * VT_LD];
    int b = blockIdx.x >> 4;
    int kt = blockIdx.x & 15;
    size_t vbase = ((size_t)b * SQ + (size_t)kt * 128) * DD;
    int t = threadIdx.x;   // 512
    for (int i = 0; i < 8; ++i) {
        size_t fi = (size_t)i * 2048 + (size_t)t * 4;
        float4 val = *(const float4*)(v + vbase + fi);
        int kk = (int)(fi >> 7);
        int d0 = (int)(fi & 127);
        tile[(d0 + 0) * VT_LD + kk] = f2bf(val.x);
        tile[(d0 + 1) * VT_LD + kk] = f2bf(val.y);
        tile[(d0 + 2) * VT_LD + kk] = f2bf(val.z);
        tile[(d0 + 3) * VT_LD + kk] = f2bf(val.w);
    }
    __syncthreads();
    int d = t >> 2, ks = (t & 3) * 32;
    size_t obase = (size_t)b * (DD * SQ) + (size_t)d * SQ + (size_t)kt * 128 + ks;
    const unsigned short* row = tile + d * VT_LD + ks;
    #pragma unroll
    for (int j = 0; j < 4; ++j)
        *(int4*)(vt + obase + j * 8) = *(const int4*)(row + j * 8);
}

__global__ void xform_bias(const float* __restrict__ bias, const void* __restrict__ mask,
                           unsigned short* __restrict__ biasT) {
    __shared__ unsigned short T[32][XB_LD];
    int q = blockIdx.x >> 2, kc = blockIdx.x & 3;
    int k0 = kc * 512;
    int t = threadIdx.x;   // 256
    int mshift = mask_byte_shift(mask);
    const float4* src = (const float4*)(bias + ((size_t)q * SQ + k0) * BH);
    #pragma unroll
    for (int i = 0; i < 16; ++i) {
        int e4 = i * 256 + t;
        float4 v = src[e4];
        int elem = e4 * 4;
        int k = elem >> 5, b0 = elem & 31;
        T[b0 + 0][k] = f2bf(v.x); T[b0 + 1][k] = f2bf(v.y);
        T[b0 + 2][k] = f2bf(v.z); T[b0 + 3][k] = f2bf(v.w);
    }
    __syncthreads();
    const unsigned short NEGB = f2bf(-1e18f);
    int b = t >> 3;
    int toff = (t & 7) * 8;
    #pragma unroll
    for (int j = 0; j < 8; ++j) {
        int ks = j * 64 + toff;
        size_t gidx = ((size_t)b * SQ + q) * SQ + k0 + ks;
        unsigned short o[8];
        if (mshift == 2) {
            const int4* mp = (const int4*)((const int*)mask + gidx);
            int4 m0 = mp[0], m1 = mp[1];
            o[0] = m0.x ? NEGB : T[b][ks + 0];
            o[1] = m0.y ? NEGB : T[b][ks + 1];
            o[2] = m0.z ? NEGB : T[b][ks + 2];
            o[3] = m0.w ? NEGB : T[b][ks + 3];
            o[4] = m1.x ? NEGB : T[b][ks + 4];
            o[5] = m1.y ? NEGB : T[b][ks + 5];
            o[6] = m1.z ? NEGB : T[b][ks + 6];
            o[7] = m1.w ? NEGB : T[b][ks + 7];
        } else {
            uint2 mw = *(const uint2*)((const unsigned char*)mask + gidx);
            #pragma unroll
            for (int by = 0; by < 4; ++by) {
                o[by]     = ((mw.x >> (by * 8)) & 0xFF) ? NEGB : T[b][ks + by];
                o[4 + by] = ((mw.y >> (by * 8)) & 0xFF) ? NEGB : T[b][ks + 4 + by];
            }
        }
        us8 pk;
        #pragma unroll
        for (int c = 0; c < 8; ++c) pk[c] = o[c];
        __builtin_nontemporal_store(pk, (us8*)(biasT + gidx));
    }
}

__global__ __launch_bounds__(512, 4) void attn_scores_f32(
    const unsigned short* __restrict__ Qb, const unsigned short* __restrict__ Kb,
    const unsigned short* __restrict__ biasT, float* __restrict__ rowinvG,
    float* __restrict__ Ef) {
    __shared__ float rs[32];
    int b = blockIdx.x >> 6, qt = blockIdx.x & 63;
    int q0 = qt * 32;
    int tid = threadIdx.x, lane = tid & 63, w = tid >> 6;
    int l15 = lane & 15, lhi = lane >> 4;
    if (tid < 32) rs[tid] = 0.f;
    __syncthreads();
    size_t headQK = (size_t)b * (SQ * DD);
    size_t ebase = (size_t)b * SQ * SQ;
    bf16x8 qf[2][4];
    #pragma unroll
    for (int qg = 0; qg < 2; ++qg)
        #pragma unroll
        for (int ds = 0; ds < 4; ++ds)
            qf[qg][ds] = *(const bf16x8*)(Qb + headQK +
                           (size_t)(q0 + qg * 16 + l15) * DD + ds * 32 + lhi * 8);
    float ps[2] = {0.f, 0.f};
    #pragma unroll 1
    for (int kt = 0; kt < 16; ++kt) {
        int kbase = w * 256 + kt * 16;
        bf16x8 kf[4];
        #pragma unroll
        for (int ds = 0; ds < 4; ++ds)
            kf[ds] = *(const bf16x8*)(Kb + headQK +
                       (size_t)(kbase + l15) * DD + ds * 32 + lhi * 8);
        #pragma unroll
        for (int qg = 0; qg < 2; ++qg) {
            f32x4 acc = {0.f, 0.f, 0.f, 0.f};
            #pragma unroll
            for (int ds = 0; ds < 4; ++ds)
                acc = __builtin_amdgcn_mfma_f32_16x16x32_bf16(kf[ds], qf[qg][ds], acc, 0, 0, 0);
            int q = q0 + qg * 16 + l15;
            int k = kbase + lhi * 4;
            size_t eidx = ebase + (size_t)q * SQ + k;
            ushort4 bv = *(const ushort4*)(biasT + eidx);
            float u0 = __expf(acc[0] * SCALE + bf2f(bv.x));
            float u1 = __expf(acc[1] * SCALE + bf2f(bv.y));
            float u2 = __expf(acc[2] * SCALE + bf2f(bv.z));
            float u3 = __expf(acc[3] * SCALE + bf2f(bv.w));
            ps[qg] += (u0 + u1) + (u2 + u3);
            float4 st = {u0, u1, u2, u3};
            *(float4*)(Ef + eidx) = st;
        }
    }
    #pragma unroll
    for (int qg = 0; qg < 2; ++qg) {
        float v = ps[qg];
        v += __shfl_xor(v, 16);
        v += __shfl_xor(v, 32);
        if (lane < 16) atomicAdd(&rs[qg * 16 + l15], v);
    }
    __syncthreads();
    if (tid < 32) rowinvG[(size_t)b * SQ + q0 + tid] = 1.0f / rs[tid];
}

__global__ __launch_bounds__(512, 4) void attn_pv_f32(
    const unsigned short* __restrict__ VT, const float* __restrict__ rowinvG,
    float* __restrict__ Ef, float* __restrict__ outp, float* __restrict__ attnp) {
    int b = blockIdx.x >> 6, qt = blockIdx.x & 63;
    int q0 = qt * 32;
    int tid = threadIdx.x, lane = tid & 63, w = tid >> 6;
    int qg = w >> 2, ds = w & 3;
    int l15 = lane & 15, lhi = lane >> 4;
    size_t ebase = (size_t)b * SQ * SQ;
    size_t vbase = (size_t)b * (DD * SQ);
    f32x4 acc[2] = {{0.f,0.f,0.f,0.f},{0.f,0.f,0.f,0.f}};
    const size_t arow = ebase + (size_t)(q0 + qg * 16 + l15) * SQ;
    #pragma unroll 2
    for (int kt = 0; kt < 64; ++kt) {
        int k = kt * 32 + lhi * 8;
        float4 a0 = *(const float4*)(Ef + arow + k);
        float4 a1 = *(const float4*)(Ef + arow + k + 4);
        bf16x8 af;
        af[0] = (short)f2bf(a0.x); af[1] = (short)f2bf(a0.y);
        af[2] = (short)f2bf(a0.z); af[3] = (short)f2bf(a0.w);
        af[4] = (short)f2bf(a1.x); af[5] = (short)f2bf(a1.y);
        af[6] = (short)f2bf(a1.z); af[7] = (short)f2bf(a1.w);
        #pragma unroll
        for (int m = 0; m < 2; ++m) {
            bf16x8 bfr = *(const bf16x8*)(VT + vbase +
                           (size_t)(ds * 32 + m * 16 + l15) * SQ + k);
            acc[m] = __builtin_amdgcn_mfma_f32_16x16x32_bf16(af, bfr, acc[m], 0, 0, 0);
        }
    }
    #pragma unroll
    for (int m = 0; m < 2; ++m)
        #pragma unroll
        for (int r = 0; r < 4; ++r) {
            int q = q0 + qg * 16 + lhi * 4 + r;
            float inv = rowinvG[(size_t)b * SQ + q];
            outp[((size_t)b * SQ + q) * DD + ds * 32 + m * 16 + l15] = acc[m][r] * inv;
        }
    __syncthreads();
    int row = tid >> 4;
    int coff = (tid & 15) * 4;
    float inv = rowinvG[(size_t)b * SQ + q0 + row];
    size_t rbase = ebase + (size_t)(q0 + row) * SQ;
    #pragma unroll 4
    for (int it = 0; it < 32; ++it) {
        int k = it * 64 + coff;
        float4 u = *(const float4*)(Ef + rbase + k);
        u.x *= inv; u.y *= inv; u.z *= inv; u.w *= inv;
        *(float4*)(attnp + rbase + k) = u;
    }
}

// ---------------- naive last-resort ----------------
__global__ void attn_naive(const float* __restrict__ Q, const float* __restrict__ K,
                           const float* __restrict__ V, const float* __restrict__ bias,
                           const void* __restrict__ mask,
                           float* __restrict__ outp, float* __restrict__ attnp) {
    __shared__ float qrow[DD];
    __shared__ float prow[SQ];
    __shared__ float red[4];
    int b = blockIdx.x >> 11;
    int q = blockIdx.x & 2047;
    int tid = threadIdx.x;
    int mshift = mask_byte_shift(mask);
    const unsigned char* M = (const unsigned char*)mask;
    if (tid < DD) qrow[tid] = Q[((size_t)b * SQ + q) * DD + tid];
    __syncthreads();
    float lsum = 0.f;
    for (int k = tid; k < SQ; k += 256) {
        float s = 0.f;
        const float* kr = K + ((size_t)b * SQ + k) * DD;
        for (int d = 0; d < DD; ++d) s += qrow[d] * kr[d];
        s = s * SCALE + bias[((size_t)q * SQ + k) * BH + b];
        size_t midx = ((size_t)b * SQ + q) * SQ + k;
        float p = (M[midx << mshift] != 0) ? 0.f : __expf(s);
        prow[k] = p; lsum += p;
    }
    lsum += __shfl_xor(lsum, 1);  lsum += __shfl_xor(lsum, 2);
    lsum += __shfl_xor(lsum, 4);  lsum += __shfl_xor(lsum, 8);
    lsum += __shfl_xor(lsum, 16); lsum += __shfl_xor(lsum, 32);
    if ((tid & 63) == 0) red[tid >> 6] = lsum;
    __syncthreads();
    float inv = 1.0f / (red[0] + red[1] + red[2] + red[3]);
    for (int k = tid; k < SQ; k += 256) {
        float p = prow[k] * inv;
        prow[k] = p;
        attnp[((size_t)b * SQ + q) * SQ + k] = p;
    }
    __syncthreads();
    if (tid < DD) {
        float o = 0.f;
        for (int k = 0; k < SQ; ++k) o += prow[k] * V[((size_t)b * SQ + k) * DD + tid];
        outp[((size_t)b * SQ + q) * DD + tid] = o;
    }
}

extern "C" void kernel_launch(void* const* d_in, const int* in_sizes, int n_in,
                              void* d_out, int out_size, void* d_ws, size_t ws_size,
                              hipStream_t stream) {
    const float* Q = (const float*)d_in[0];
    const float* K = (const float*)d_in[1];
    const float* V = (const float*)d_in[2];
    const float* bias = (const float*)d_in[3];
    const void* mask = d_in[4];
    float* outp = (float*)d_out;
    float* attnp = outp + (size_t)BH * SQ * DD;

    const size_t tsz = (size_t)BH * SQ * DD;          // 8388608
    const size_t biasN = (size_t)BH * SQ * SQ;        // 134217728
    const size_t cvtB = tsz * 2 * 3;                  // 48 MB
    const size_t needF32 = cvtB + biasN * 2 + (size_t)BH * SQ * 4;   // ~319 MB
    const size_t needBF = needF32 + biasN * 2;                        // ~587 MB

    if (ws_size >= cvtB) {
        char* p = (char*)d_ws;
        unsigned short* Qbf = (unsigned short*)p;          p += tsz * 2;
        unsigned short* Kbf = (unsigned short*)p;          p += tsz * 2;
        unsigned short* VTp = (unsigned short*)p;          p += tsz * 2;
        if (ws_size >= needBF) {
            unsigned short* biasT = (unsigned short*)p;    p += biasN * 2;
            float* rowinvG = (float*)p;                    p += (size_t)BH * SQ * 4;
            unsigned short* Ebf = (unsigned short*)p;
            prep_all<<<9216, 512, 0, stream>>>(Q, K, V, bias, mask, Qbf, Kbf, VTp, biasT);
            hipError_t e1 = hipFuncSetAttribute((const void*)attn_scores,
                                hipFuncAttributeMaxDynamicSharedMemorySize, 81920);
            hipError_t e2 = hipFuncSetAttribute((const void*)attn_pv,
                                hipFuncAttributeMaxDynamicSharedMemorySize, 65536);
            (void)e1; (void)e2;
            attn_scores<<<1024, 512, 81920, stream>>>(Qbf, Kbf, biasT, rowinvG, Ebf);
            attn_pv<<<512, 512, 65536, stream>>>(Ebf, VTp, rowinvG, outp, attnp);
        } else if (ws_size >= needF32) {
            unsigned short* biasT = (unsigned short*)p;    p += biasN * 2;
            float* rowinvG = (float*)p;                    p += (size_t)BH * SQ * 4;
            cvt_qk<<<4096, 256, 0, stream>>>(Q, K, Qbf, Kbf);
            cvt_vt<<<512, 512, 0, stream>>>(V, VTp);
            xform_bias<<<8192, 256, 0, stream>>>(bias, mask, biasT);
            attn_scores_f32<<<2048, 512, 0, stream>>>(Qbf, Kbf, biasT, rowinvG, attnp);
            attn_pv_f32<<<2048, 512, 0, stream>>>(VTp, rowinvG, attnp, outp, attnp);
        } else {
            attn_naive<<<BH * SQ, 256, 0, stream>>>(Q, K, V, bias, mask, outp, attnp);
        }
    } else {
        attn_naive<<<BH * SQ, 256, 0, stream>>>(Q, K, V, bias, mask, outp, attnp);
    }
}